// Round 12
// baseline (860.373 us; speedup 1.0000x reference)
//
#include <hip/hip_runtime.h>
#include <hip/hip_bf16.h>
#include <cstdint>

#define SENT_LEN   256
#define SENT_BATCH 64
#define WORD_LEN   16
#define EMB        128
#define HID        256
#define CEMB       64
#define CHID       128
#define TAGS       50
#define K_IN       (EMB + CHID)   // 256
#define LOG2E      1.44269504f
#define N2LOG2E    -2.88539008f   // -2*log2(e)

typedef __attribute__((ext_vector_type(8))) short short8;
typedef __attribute__((ext_vector_type(4))) float f32x4;
typedef __attribute__((ext_vector_type(4))) int   i32x4;
typedef __attribute__((ext_vector_type(2))) long  lng2;

__device__ __forceinline__ float rcpf(float x) { return __builtin_amdgcn_rcpf(x); }
// inputs pre-scaled by log2e: sig2(xl) = sigmoid(xl/log2e)
__device__ __forceinline__ float sig2(float xl) {
    return rcpf(1.f + __builtin_amdgcn_exp2f(-xl));
}
// tanh via sigmoid identity, clamp-free: tanh(x) = 2*sigmoid(2x)-1.
__device__ __forceinline__ float tanh2(float xl) {
    float e = __builtin_amdgcn_exp2f(-(xl + xl));
    return 2.f * rcpf(1.f + e) - 1.f;
}
__device__ __forceinline__ float lstm_act(float gi, float gf, float gg, float go, float& cst) {
    float c = sig2(gf) * cst + sig2(gi) * tanh2(gg);
    cst = c;
    float tc = 2.f * rcpf(1.f + __builtin_amdgcn_exp2f(N2LOG2E * c)) - 1.f;
    return sig2(go) * tc;
}
__device__ __forceinline__ float bf_lo(unsigned u) { return __uint_as_float(u << 16); }
__device__ __forceinline__ float bf_hi(unsigned u) { return __uint_as_float(u & 0xffff0000u); }
// branch-free RNE bf16 (finite inputs only)
__device__ __forceinline__ unsigned short f2bfu(float f) {
    unsigned u = __float_as_uint(f);
    u += 0x7fff + ((u >> 16) & 1);
    return (unsigned short)(u >> 16);
}
// CK-style barrier: drains LDS (lgkmcnt) only — global prefetches stay in flight.
__device__ __forceinline__ void block_sync_lds() {
    asm volatile("s_waitcnt lgkmcnt(0)\ns_barrier" ::: "memory");
}
// 16-byte K-fragment i8 MFMA: native gfx950 K=64 instruction (single issue).
__device__ __forceinline__ i32x4 mfma_i8_k64(lng2 a, lng2 b, i32x4 c) {
    i32x4 av = __builtin_bit_cast(i32x4, a);
    i32x4 bv = __builtin_bit_cast(i32x4, b);
    return __builtin_amdgcn_mfma_i32_16x16x64_i8(av, bv, c, 0, 0, 0);
}
// quad_perm broadcast of quad-lane Q (pure-VALU cross-lane, no LDS pipe)
template<int Q> __device__ __forceinline__ float qbcast(float x) {
    return __int_as_float(__builtin_amdgcn_mov_dpp(
        __float_as_int(x), Q * 0x55, 0xF, 0xF, false));
}

// ---------------- K1: merged prep. Blocks 0-127: pre8 for char_lstm.
// Blocks 128-255: 8 rows each of {i8 quant of Whh_w, fragment-order bf16 Wih_w}.
__global__ __launch_bounds__(512) void prep_all(
        const float* __restrict__ Wih_c, const float* __restrict__ char_emb,
        const float* __restrict__ bih_c, const float* __restrict__ bhh_c,
        const float* __restrict__ Whh_w, const float* __restrict__ Wih_w,
        float* __restrict__ pre8, signed char* __restrict__ wq,
        float* __restrict__ sw, unsigned short* __restrict__ wihb) {
    int bid = blockIdx.x;
    int tid = threadIdx.x;
    if (bid < 128) {
        // pre8[ch*512 + (j*4+gt)] = s_e * LOG2E * (b_c[g] + Wih_c[g]·char_emb[ch])
        int ch = bid, g = tid;
        float acc = bih_c[g] + bhh_c[g];
        const float4* w4 = reinterpret_cast<const float4*>(Wih_c + (size_t)g * CEMB);
        const float4* e4 = reinterpret_cast<const float4*>(char_emb + (size_t)ch * CEMB);
#pragma unroll
        for (int k = 0; k < CEMB / 4; k++) {
            float4 wv = w4[k], ev = e4[k];
            acc += wv.x * ev.x; acc += wv.y * ev.y;
            acc += wv.z * ev.z; acc += wv.w * ev.w;
        }
        int gt = g >> 7, j = g & 127;
        float s_e = (gt == 2) ? -2.f : -1.f;
        pre8[((ch * 128) + j) * 4 + gt] = acc * LOG2E * s_e;
    } else {
        int g = (bid - 128) * 8 + (tid >> 6);   // Whh_w/Wih_w row
        int lane = tid & 63;
        float4 v = reinterpret_cast<const float4*>(Whh_w + (size_t)g * HID)[lane];
        float m = fmaxf(fmaxf(fabsf(v.x), fabsf(v.y)), fmaxf(fabsf(v.z), fabsf(v.w)));
#pragma unroll
        for (int off = 32; off; off >>= 1) m = fmaxf(m, __shfl_xor(m, off, 64));
        m = fmaxf(m, 1e-20f);
        float inv = 127.f / m;
        int q0 = __float2int_rn(v.x * inv), q1 = __float2int_rn(v.y * inv);
        int q2 = __float2int_rn(v.z * inv), q3 = __float2int_rn(v.w * inv);
        int packed = (q0 & 255) | ((q1 & 255) << 8) | ((q2 & 255) << 16) | ((q3 & 255) << 24);
        reinterpret_cast<int*>(wq)[g * 64 + lane] = packed;
        if (lane == 0) sw[g] = m / 127.f;
        // fragment-order bf16 copy of Wih_w row g
        float4 wv = reinterpret_cast<const float4*>(Wih_w + (size_t)g * K_IN)[lane];
        uint2 p;
        p.x = (unsigned)f2bfu(wv.x) | ((unsigned)f2bfu(wv.y) << 16);
        p.y = (unsigned)f2bfu(wv.z) | ((unsigned)f2bfu(wv.w) << 16);
        int n2 = g >> 8, j = g & 255, jt = j >> 4, l15 = j & 15;
        int k0 = lane * 4;
        int kt = k0 >> 5, lqf = (k0 >> 3) & 3;
        size_t fidx = ((size_t)(jt * 4 + n2) * 8 + kt) * 64 + (lqf * 16 + l15);
        char* dst = (char*)wihb + fidx * 16 + (size_t)(k0 & 4) * 2;
        *reinterpret_cast<uint2*>(dst) = p;
    }
}

// ---------------- K2: char LSTM (proven R0 dot4 loop) + FUSED xw GEMM epilogue.
// 256 blocks x 1 chain, 512 threads (8 waves = 2/SIMD).
__global__ __launch_bounds__(512, 1) void char_lstm(
        const int* __restrict__ words, const float* __restrict__ Whh_c,
        const float* __restrict__ pre8, const int* __restrict__ sentences,
        const float* __restrict__ word_emb, const unsigned short* __restrict__ wihb,
        const float* __restrict__ bih_w, const float* __restrict__ bhh_w,
        uint2* __restrict__ xw8) {
    int t    = blockIdx.x;               // chain
    int tid  = threadIdx.x;
    int lane = tid & 63, w = tid >> 6;   // 8 waves
    int nt   = lane & 3;
    int j    = w * 16 + (lane >> 2);
    int g    = nt * 128 + j;             // this lane's gate row

    __shared__ __align__(16) signed char hv[2][128];        // h as i8, dbuf
    __shared__ __align__(16) unsigned short xls[64][264];   // x rows bf16, pad 8

    // ---- per-lane i8 quant of this lane's Whh_c row
    const float4* wr = reinterpret_cast<const float4*>(Whh_c + (size_t)g * CHID);
    float mx = 1e-20f;
#pragma unroll
    for (int q = 0; q < 32; q++) {
        float4 f = wr[q];
        mx = fmaxf(mx, fmaxf(fmaxf(fabsf(f.x), fabsf(f.y)), fmaxf(fabsf(f.z), fabsf(f.w))));
    }
    float inv = 127.f / mx;
    int wqr[32];
#pragma unroll
    for (int q = 0; q < 32; q++) {
        float4 f = wr[q];
        wqr[q] = (__float2int_rn(f.x * inv) & 255)
               | ((__float2int_rn(f.y * inv) & 255) << 8)
               | ((__float2int_rn(f.z * inv) & 255) << 16)
               | ((__float2int_rn(f.w * inv) & 255) << 24);
    }
    float s_e   = (nt == 2) ? -2.f : -1.f;
    float swl_s = s_e * mx * (LOG2E / (127.f * 127.f));
    float m_a   = (nt == 2) ?  2.f :  1.f;
    float b_a   = (nt == 2) ? -1.f :  0.f;

    // ---- stage embedding half of x: xls[b][0:128] = bf16(word_emb[sid[b]])
    {
        int b  = tid >> 3;          // 0..63
        int c8 = tid & 7;           // 16 floats per thread
        int sid = sentences[t * 64 + b];
        const float4* ep = reinterpret_cast<const float4*>(
            word_emb + (size_t)sid * EMB + c8 * 16);
        float4 e0 = ep[0], e1 = ep[1], e2 = ep[2], e3 = ep[3];
        short8 v0, v1;
        v0[0] = (short)f2bfu(e0.x); v0[1] = (short)f2bfu(e0.y);
        v0[2] = (short)f2bfu(e0.z); v0[3] = (short)f2bfu(e0.w);
        v0[4] = (short)f2bfu(e1.x); v0[5] = (short)f2bfu(e1.y);
        v0[6] = (short)f2bfu(e1.z); v0[7] = (short)f2bfu(e1.w);
        v1[0] = (short)f2bfu(e2.x); v1[1] = (short)f2bfu(e2.y);
        v1[2] = (short)f2bfu(e2.z); v1[3] = (short)f2bfu(e2.w);
        v1[4] = (short)f2bfu(e3.x); v1[5] = (short)f2bfu(e3.y);
        v1[6] = (short)f2bfu(e3.z); v1[7] = (short)f2bfu(e3.w);
        *reinterpret_cast<short8*>(&xls[b][c8 * 16])     = v0;
        *reinterpret_cast<short8*>(&xls[b][c8 * 16 + 8]) = v1;
    }

    if (tid < 64) { reinterpret_cast<int*>(hv)[tid] = 0; }

    float cst = 0.f;
    int cid0 = words[t];
    int cid1 = words[SENT_LEN + t];
    float pl0 = pre8[(size_t)cid0 * 512 + tid];   // this lane's gate pre-input (folded)
    float pl1 = pre8[(size_t)cid1 * 512 + tid];
    int ci2 = words[2 * SENT_LEN + t];
    int ci3 = words[3 * SENT_LEN + t];
    __syncthreads();

    for (int u = 0; u < 512; u++) {          // steps 2u (A), 2u+1 (B)
        float pf0 = pre8[(size_t)ci2 * 512 + tid];
        float pf1 = pre8[(size_t)ci3 * 512 + tid];
        ci2 = words[(((u << 1) + 4) & 1023) * SENT_LEN + t];
        ci3 = words[(((u << 1) + 5) & 1023) * SENT_LEN + t];

        {   // step A: read hv[0] -> write hv[1]
            const i32x4* hp = reinterpret_cast<const i32x4*>(hv[0]);
            int a0 = 0, a1 = 0, a2 = 0, a3 = 0;
#pragma unroll
            for (int q = 0; q < 8; q++) {
                i32x4 hq = hp[q];
                a0 = __builtin_amdgcn_sdot4(hq.x, wqr[q * 4 + 0], a0, false);
                a1 = __builtin_amdgcn_sdot4(hq.y, wqr[q * 4 + 1], a1, false);
                a2 = __builtin_amdgcn_sdot4(hq.z, wqr[q * 4 + 2], a2, false);
                a3 = __builtin_amdgcn_sdot4(hq.w, wqr[q * 4 + 3], a3, false);
            }
            int s = (a0 + a1) + (a2 + a3);
            float e  = __builtin_amdgcn_exp2f(fmaf((float)s, swl_s, pl0));
            float av = m_a * rcpf(1.f + e) + b_a;     // own gate's nonlinearity
            float qi = qbcast<0>(av);                 // sig(i)
            float qf = qbcast<1>(av);                 // sig(f)
            float qg = qbcast<2>(av);                 // tanh(g)
            float qo = qbcast<3>(av);                 // sig(o)
            float c  = fmaf(qf, cst, qi * qg);
            cst = c;
            float tc = 2.f * rcpf(1.f + __builtin_amdgcn_exp2f(N2LOG2E * c)) - 1.f;
            float h  = qo * tc;
            if (nt == 0)
                hv[1][j] = (signed char)__float2int_rn(h * 127.f);
            block_sync_lds();
        }
        {   // step B: read hv[1] -> write hv[0]
            const i32x4* hp = reinterpret_cast<const i32x4*>(hv[1]);
            int a0 = 0, a1 = 0, a2 = 0, a3 = 0;
#pragma unroll
            for (int q = 0; q < 8; q++) {
                i32x4 hq = hp[q];
                a0 = __builtin_amdgcn_sdot4(hq.x, wqr[q * 4 + 0], a0, false);
                a1 = __builtin_amdgcn_sdot4(hq.y, wqr[q * 4 + 1], a1, false);
                a2 = __builtin_amdgcn_sdot4(hq.z, wqr[q * 4 + 2], a2, false);
                a3 = __builtin_amdgcn_sdot4(hq.w, wqr[q * 4 + 3], a3, false);
            }
            int s = (a0 + a1) + (a2 + a3);
            float e  = __builtin_amdgcn_exp2f(fmaf((float)s, swl_s, pl1));
            float av = m_a * rcpf(1.f + e) + b_a;
            float qi = qbcast<0>(av);
            float qf = qbcast<1>(av);
            float qg = qbcast<2>(av);
            float qo = qbcast<3>(av);
            float c  = fmaf(qf, cst, qi * qg);
            cst = c;
            float tc = 2.f * rcpf(1.f + __builtin_amdgcn_exp2f(N2LOG2E * c)) - 1.f;
            float h  = qo * tc;
            if (nt == 0) {
                hv[0][j] = (signed char)__float2int_rn(h * 127.f);
                if ((u & 7) == 7)
                    xls[u >> 3][128 + j] = f2bfu(h);   // x row's char half (bf16)
            }
            block_sync_lds();
        }
        pl0 = pf0; pl1 = pf1;
    }

    // ---- fused XW GEMM epilogue (64 rows x 1024 gates, K=256).
    {
        int l15 = lane & 15, lq = lane >> 4;
        int mt  = w & 3;
        short8 af[8];
#pragma unroll
        for (int kt = 0; kt < 8; kt++)
            af[kt] = *reinterpret_cast<const short8*>(&xls[mt * 16 + l15][kt * 32 + lq * 8]);
        const short8* bF = reinterpret_cast<const short8*>(wihb);
#pragma unroll 1
        for (int jt = (w >> 2); jt < 16; jt += 2) {
            int j0 = jt * 16;
            const short8* bJ = bF + (size_t)jt * 4 * 8 * 64 + lane;
            f32x4 acc[4] = {{0.f,0.f,0.f,0.f},{0.f,0.f,0.f,0.f},
                            {0.f,0.f,0.f,0.f},{0.f,0.f,0.f,0.f}};
#pragma unroll
            for (int kt = 0; kt < 8; kt++) {
#pragma unroll
                for (int n2 = 0; n2 < 4; n2++) {
                    short8 bf = bJ[(n2 * 8 + kt) * 64];
                    acc[n2] = __builtin_amdgcn_mfma_f32_16x16x32_bf16(
                        af[kt], bf, acc[n2], 0, 0, 0);
                }
            }
            float bb[4];
#pragma unroll
            for (int n2 = 0; n2 < 4; n2++)
                bb[n2] = bih_w[n2 * 256 + j0 + l15] + bhh_w[n2 * 256 + j0 + l15];
#pragma unroll
            for (int r = 0; r < 4; r++) {
                int br = mt * 16 + lq * 4 + r;       // chain index within this t
                uint2 o;
                o.x = (unsigned)f2bfu((acc[0][r] + bb[0]) * LOG2E)
                    | ((unsigned)f2bfu((acc[1][r] + bb[1]) * LOG2E) << 16);
                o.y = (unsigned)f2bfu((acc[2][r] + bb[2]) * LOG2E)
                    | ((unsigned)f2bfu((acc[3][r] + bb[3]) * LOG2E) << 16);
                xw8[((size_t)br * SENT_LEN + t) * 256 + j0 + l15] = o;
            }
        }
    }
}

// ---------------- K4: word LSTM. 64 blocks x 1 chain, 1024 threads (16 waves) —
// R10's proven config: 4 waves/SIMD TLP hides the 4-deep MFMA chain + LDS latency.
__global__ __launch_bounds__(1024, 1) void word_lstm(
        const uint2* __restrict__ xw8, const signed char* __restrict__ wq,
        const float* __restrict__ sw, float* __restrict__ h_out) {
    int b    = blockIdx.x;               // chain 0..63
    int tid  = threadIdx.x;
    int lane = tid & 63, w = tid >> 6;   // 16 waves
    int l15  = lane & 15, lq = lane >> 4;
    int j    = w * 16 + l15;

    __shared__ __align__(16) signed char hv[2][256];   // h as i8, dbuf, 512 B

    lng2 bfr[4][4];
    float swl[4];
#pragma unroll
    for (int nt = 0; nt < 4; nt++) {
        int g = nt * 256 + j;
        swl[nt] = sw[g] * (LOG2E / 127.f);
#pragma unroll
        for (int kt = 0; kt < 4; kt++)
            bfr[nt][kt] = reinterpret_cast<const lng2*>(wq + (size_t)g * HID + kt * 64 + lq * 16)[0];
    }
    if (tid < 128) { reinterpret_cast<int*>(hv)[tid] = 0; }

    const uint2* xwb = xw8 + (size_t)b * SENT_LEN * 256;   // this block's stream
    float cst = 0.f;
    uint2 xq0 = xwb[0 * 256 + j];
    uint2 xq1 = xwb[1 * 256 + j];
    uint2 xq2 = xwb[2 * 256 + j];
    uint2 xq3 = xwb[3 * 256 + j];
    __syncthreads();

    for (int u = 0; u < 128; u++) {          // steps 2u (A), 2u+1 (B)
        uint2 xn0 = xwb[((((u << 1) + 4) & 255)) * 256 + j];
        uint2 xn1 = xwb[((((u << 1) + 5) & 255)) * 256 + j];

        {   // step A: read hv[0] -> write hv[1]
            const lng2* hp = reinterpret_cast<const lng2*>(hv[0]);
            i32x4 acc[4] = {};
#pragma unroll
            for (int kt = 0; kt < 4; kt++) {
                lng2 a = hp[kt * 4 + lq];
#pragma unroll
                for (int nt = 0; nt < 4; nt++)
                    acc[nt] = mfma_i8_k64(a, bfr[nt][kt], acc[nt]);
            }
            float gi = (float)acc[0][0] * swl[0] + bf_lo(xq0.x);
            float gf = (float)acc[1][0] * swl[1] + bf_hi(xq0.x);
            float gg = (float)acc[2][0] * swl[2] + bf_lo(xq0.y);
            float go = (float)acc[3][0] * swl[3] + bf_hi(xq0.y);
            float h = lstm_act(gi, gf, gg, go, cst);
            if (lq == 0) {
                h_out[((size_t)(u << 1) * SENT_BATCH + b) * HID + j] = h;
                hv[1][j] = (signed char)__float2int_rn(h * 127.f);
            }
            block_sync_lds();
        }
        {   // step B: read hv[1] -> write hv[0]
            const lng2* hp = reinterpret_cast<const lng2*>(hv[1]);
            i32x4 acc[4] = {};
#pragma unroll
            for (int kt = 0; kt < 4; kt++) {
                lng2 a = hp[kt * 4 + lq];
#pragma unroll
                for (int nt = 0; nt < 4; nt++)
                    acc[nt] = mfma_i8_k64(a, bfr[nt][kt], acc[nt]);
            }
            float gi = (float)acc[0][0] * swl[0] + bf_lo(xq1.x);
            float gf = (float)acc[1][0] * swl[1] + bf_hi(xq1.x);
            float gg = (float)acc[2][0] * swl[2] + bf_lo(xq1.y);
            float go = (float)acc[3][0] * swl[3] + bf_hi(xq1.y);
            float h = lstm_act(gi, gf, gg, go, cst);
            if (lq == 0) {
                h_out[((size_t)((u << 1) + 1) * SENT_BATCH + b) * HID + j] = h;
                hv[0][j] = (signed char)__float2int_rn(h * 127.f);
            }
            block_sync_lds();
        }
        xq0 = xq2; xq1 = xq3; xq2 = xn0; xq3 = xn1;
    }
}

// ---------------- K5: tag projection + log_softmax. 8 rows/block (W_tag staging amortized).
__global__ __launch_bounds__(256) void tag_logsoftmax(
        const float* __restrict__ h_out, const float* __restrict__ W_tag,
        const float* __restrict__ b_tag, float* __restrict__ out) {
    __shared__ float wt_s[TAGS * 257];      // 51.4 KB
    __shared__ float hr_s[8 * HID];         // 8 KB
    int tid = threadIdx.x;
    int row0 = blockIdx.x * 8;
#pragma unroll 2
    for (int i = 0; i < TAGS; i++) wt_s[i * 257 + tid] = W_tag[i * HID + tid];
#pragma unroll
    for (int w = 0; w < 8; w++) hr_s[w * HID + tid] = h_out[(size_t)(row0 + w) * HID + tid];
    __syncthreads();

    int w4 = tid >> 6, l = tid & 63;
#pragma unroll
    for (int rep = 0; rep < 2; rep++) {
        int w = rep * 4 + w4;
        float acc = 0.f;
        if (l < TAGS) {
            acc = b_tag[l];
            const float* hr = hr_s + w * HID;
            const float* wr = wt_s + l * 257;
#pragma unroll 4
            for (int k = 0; k < HID; k++) acc += hr[k] * wr[k];
        }
        float m = (l < TAGS) ? acc : -1e30f;
#pragma unroll
        for (int off = 32; off; off >>= 1) m = fmaxf(m, __shfl_xor(m, off, 64));
        float e = (l < TAGS) ? __builtin_amdgcn_exp2f((acc - m) * LOG2E) : 0.f;
        float ssum = e;
#pragma unroll
        for (int off = 32; off; off >>= 1) ssum += __shfl_xor(ssum, off, 64);
        float lse = m + __logf(ssum);
        if (l < TAGS) out[(size_t)(row0 + w) * TAGS + l] = acc - lse;
    }
}

extern "C" void kernel_launch(void* const* d_in, const int* in_sizes, int n_in,
                              void* d_out, int out_size, void* d_ws, size_t ws_size,
                              hipStream_t stream) {
    (void)in_sizes; (void)n_in; (void)out_size; (void)ws_size;
    const int*   sentences = (const int*)d_in[0];
    const int*   words     = (const int*)d_in[1];
    const float* word_emb  = (const float*)d_in[4];
    const float* char_emb  = (const float*)d_in[5];
    const float* Wih_c     = (const float*)d_in[6];
    const float* Whh_c     = (const float*)d_in[7];
    const float* bih_c     = (const float*)d_in[8];
    const float* bhh_c     = (const float*)d_in[9];
    const float* Wih_w     = (const float*)d_in[10];
    const float* Whh_w     = (const float*)d_in[11];
    const float* bih_w     = (const float*)d_in[12];
    const float* bhh_w     = (const float*)d_in[13];
    const float* W_tag     = (const float*)d_in[14];
    const float* b_tag     = (const float*)d_in[15];
    float* out = (float*)d_out;

    char* ws = (char*)d_ws;
    size_t off = 0;
    float* pre8 = (float*)(ws + off);                 off += 128 * 512 * sizeof(float);      // 256 KB
    signed char* wq = (signed char*)(ws + off);       off += 1024 * 256;                     // 256 KB
    float* sw = (float*)(ws + off);                   off += 1024 * sizeof(float);           // 4 KB
    unsigned short* wihb = (unsigned short*)(ws + off); off += (size_t)1024 * K_IN * 2;      // 512 KB (fragment order)
    off = (off + 255) & ~(size_t)255;
    uint2* xw8 = (uint2*)(ws + off);                  off += (size_t)SENT_LEN * SENT_BATCH * 256 * sizeof(uint2);  // 33.5 MB
    float* h_out = (float*)(ws + off);                off += (size_t)SENT_LEN * SENT_BATCH * HID * sizeof(float);  // 16.8 MB

    hipLaunchKernelGGL(prep_all, dim3(256), dim3(512), 0, stream,
                       Wih_c, char_emb, bih_c, bhh_c, Whh_w, Wih_w,
                       pre8, wq, sw, wihb);
    hipLaunchKernelGGL(char_lstm, dim3(256), dim3(512), 0, stream,
                       words, Whh_c, pre8, sentences, word_emb, wihb, bih_w, bhh_w, xw8);
    hipLaunchKernelGGL(word_lstm, dim3(SENT_BATCH), dim3(1024), 0, stream,
                       xw8, wq, sw, h_out);
    hipLaunchKernelGGL(tag_logsoftmax, dim3((SENT_LEN * SENT_BATCH) / 8), dim3(256), 0, stream,
                       h_out, W_tag, b_tag, out);
}

// Round 14
// 806.773 us; speedup vs baseline: 1.0664x; 1.0664x over previous
//
#include <hip/hip_runtime.h>
#include <hip/hip_bf16.h>
#include <cstdint>

#define SENT_LEN   256
#define SENT_BATCH 64
#define WORD_LEN   16
#define EMB        128
#define HID        256
#define CEMB       64
#define CHID       128
#define TAGS       50
#define K_IN       (EMB + CHID)   // 256
#define LOG2E      1.44269504f
#define N2LOG2E    -2.88539008f   // -2*log2(e)

typedef __attribute__((ext_vector_type(8))) short short8;
typedef __attribute__((ext_vector_type(4))) float f32x4;
typedef __attribute__((ext_vector_type(4))) int   i32x4;
typedef __attribute__((ext_vector_type(2))) long  lng2;

__device__ __forceinline__ float rcpf(float x) { return __builtin_amdgcn_rcpf(x); }
// inputs pre-scaled by log2e: sig2(xl) = sigmoid(xl/log2e)
__device__ __forceinline__ float sig2(float xl) {
    return rcpf(1.f + __builtin_amdgcn_exp2f(-xl));
}
// tanh via sigmoid identity, clamp-free: tanh(x) = 2*sigmoid(2x)-1.
__device__ __forceinline__ float tanh2(float xl) {
    float e = __builtin_amdgcn_exp2f(-(xl + xl));
    return 2.f * rcpf(1.f + e) - 1.f;
}
__device__ __forceinline__ float lstm_act(float gi, float gf, float gg, float go, float& cst) {
    float c = sig2(gf) * cst + sig2(gi) * tanh2(gg);
    cst = c;
    float tc = 2.f * rcpf(1.f + __builtin_amdgcn_exp2f(N2LOG2E * c)) - 1.f;
    return sig2(go) * tc;
}
__device__ __forceinline__ float bf_lo(unsigned u) { return __uint_as_float(u << 16); }
__device__ __forceinline__ float bf_hi(unsigned u) { return __uint_as_float(u & 0xffff0000u); }
// branch-free RNE bf16 (finite inputs only)
__device__ __forceinline__ unsigned short f2bfu(float f) {
    unsigned u = __float_as_uint(f);
    u += 0x7fff + ((u >> 16) & 1);
    return (unsigned short)(u >> 16);
}
// CK-style barrier: drains LDS (lgkmcnt) only — global prefetches stay in flight.
__device__ __forceinline__ void block_sync_lds() {
    asm volatile("s_waitcnt lgkmcnt(0)\ns_barrier" ::: "memory");
}
// 16-byte K-fragment i8 MFMA: native gfx950 K=64 instruction (single issue).
// Shared A/B k-permutation (lane chunk (l>>4)*16+p <-> source k = base+lq*16+p)
// preserves the dot; integer accumulate -> bit-identical to the chained K=32 pair.
__device__ __forceinline__ i32x4 mfma_i8_k64(lng2 a, lng2 b, i32x4 c) {
    i32x4 av = __builtin_bit_cast(i32x4, a);
    i32x4 bv = __builtin_bit_cast(i32x4, b);
    return __builtin_amdgcn_mfma_i32_16x16x64_i8(av, bv, c, 0, 0, 0);
}
// quad_perm broadcast of quad-lane Q (pure-VALU cross-lane, no LDS pipe)
template<int Q> __device__ __forceinline__ float qbcast(float x) {
    return __int_as_float(__builtin_amdgcn_mov_dpp(
        __float_as_int(x), Q * 0x55, 0xF, 0xF, false));
}

// ---------------- K1a: pre8[ch*512 + (j*4+gt)] = s_e * LOG2E*(b_c[g] + Wih_c[g]·char_emb[ch])
// s_e = -2 for the g-gate (tanh), -1 otherwise. float4 loads; fma order as scalar loop.
__global__ void prep_char(const float* __restrict__ Wih_c, const float* __restrict__ char_emb,
                          const float* __restrict__ bih_c, const float* __restrict__ bhh_c,
                          float* __restrict__ pre8) {
    int ch = blockIdx.x;      // 128
    int g  = threadIdx.x;     // 512
    float acc = bih_c[g] + bhh_c[g];
    const float4* w4 = reinterpret_cast<const float4*>(Wih_c + (size_t)g * CEMB);
    const float4* e4 = reinterpret_cast<const float4*>(char_emb + (size_t)ch * CEMB);
#pragma unroll
    for (int k = 0; k < CEMB / 4; k++) {
        float4 wv = w4[k], ev = e4[k];
        acc += wv.x * ev.x; acc += wv.y * ev.y;
        acc += wv.z * ev.z; acc += wv.w * ev.w;
    }
    int gt = g >> 7, j = g & 127;
    float s_e = (gt == 2) ? -2.f : -1.f;
    pre8[((ch * 128) + j) * 4 + gt] = acc * LOG2E * s_e;
}

// ---------------- K1b: i8 quant of Whh_w + MFMA-FRAGMENT-ORDER bf16 copy of Wih_w.
// wihbF[((jt*4+n2)*8+kt)*64 + lane] = 16B frag: B-row n2*256+jt*16+(lane&15),
// k = kt*32+(lane>>4)*8 .. +7. Epilogue B loads become lane-contiguous (coalesced).
__global__ void prep_wq(const float* __restrict__ Whh_w, const float* __restrict__ Wih_w,
                        signed char* __restrict__ wq, float* __restrict__ sw,
                        unsigned short* __restrict__ wihb) {
    int g = blockIdx.x;
    int lane = threadIdx.x;   // 64
    float4 v = reinterpret_cast<const float4*>(Whh_w + (size_t)g * HID)[lane];
    float m = fmaxf(fmaxf(fabsf(v.x), fabsf(v.y)), fmaxf(fabsf(v.z), fabsf(v.w)));
#pragma unroll
    for (int off = 32; off; off >>= 1) m = fmaxf(m, __shfl_xor(m, off, 64));
    m = fmaxf(m, 1e-20f);
    float inv = 127.f / m;
    int q0 = __float2int_rn(v.x * inv), q1 = __float2int_rn(v.y * inv);
    int q2 = __float2int_rn(v.z * inv), q3 = __float2int_rn(v.w * inv);
    int packed = (q0 & 255) | ((q1 & 255) << 8) | ((q2 & 255) << 16) | ((q3 & 255) << 24);
    reinterpret_cast<int*>(wq)[g * 64 + lane] = packed;
    if (lane == 0) sw[g] = m / 127.f;
    // fragment-order bf16 copy of Wih_w row g (bit-identical values to f2bfu staging)
    float4 wv = reinterpret_cast<const float4*>(Wih_w + (size_t)g * K_IN)[lane];
    uint2 p;
    p.x = (unsigned)f2bfu(wv.x) | ((unsigned)f2bfu(wv.y) << 16);
    p.y = (unsigned)f2bfu(wv.z) | ((unsigned)f2bfu(wv.w) << 16);
    int n2 = g >> 8, j = g & 255, jt = j >> 4, l15 = j & 15;
    int k0 = lane * 4;
    int kt = k0 >> 5, lqf = (k0 >> 3) & 3;
    size_t fidx = ((size_t)(jt * 4 + n2) * 8 + kt) * 64 + (lqf * 16 + l15);
    char* dst = (char*)wihb + fidx * 16 + (size_t)(k0 & 4) * 2;
    *reinterpret_cast<uint2*>(dst) = p;
}

// ---------------- K2: char LSTM (proven R0 dot4 loop) + FUSED xw GEMM epilogue.
// 256 blocks x 1 chain, 512 threads (8 waves = 2/SIMD).
// Main loop: ONE GATE PER LANE, 32 sdot4/lane/step, h i8 in LDS (dbuf).
// x rows ([bf16 emb | bf16 h_final]) kept in xls[64][264] (+8 pad); after the final
// barrier the block computes this t's whole xw8 slab (64x1024, K=256) with bf16 MFMA.
// B frags stream COALESCED from the fragment-order wihbF.
__global__ __launch_bounds__(512, 1) void char_lstm(
        const int* __restrict__ words, const float* __restrict__ Whh_c,
        const float* __restrict__ pre8, const int* __restrict__ sentences,
        const float* __restrict__ word_emb, const unsigned short* __restrict__ wihb,
        const float* __restrict__ bih_w, const float* __restrict__ bhh_w,
        uint2* __restrict__ xw8) {
    int t    = blockIdx.x;               // chain
    int tid  = threadIdx.x;
    int lane = tid & 63, w = tid >> 6;   // 8 waves
    int nt   = lane & 3;
    int j    = w * 16 + (lane >> 2);
    int g    = nt * 128 + j;             // this lane's gate row

    __shared__ __align__(16) signed char hv[2][128];        // h as i8, dbuf
    __shared__ __align__(16) unsigned short xls[64][264];   // x rows bf16, pad 8

    // ---- per-lane i8 quant of this lane's Whh_c row
    const float4* wr = reinterpret_cast<const float4*>(Whh_c + (size_t)g * CHID);
    float mx = 1e-20f;
#pragma unroll
    for (int q = 0; q < 32; q++) {
        float4 f = wr[q];
        mx = fmaxf(mx, fmaxf(fmaxf(fabsf(f.x), fabsf(f.y)), fmaxf(fabsf(f.z), fabsf(f.w))));
    }
    float inv = 127.f / mx;
    int wqr[32];
#pragma unroll
    for (int q = 0; q < 32; q++) {
        float4 f = wr[q];
        wqr[q] = (__float2int_rn(f.x * inv) & 255)
               | ((__float2int_rn(f.y * inv) & 255) << 8)
               | ((__float2int_rn(f.z * inv) & 255) << 16)
               | ((__float2int_rn(f.w * inv) & 255) << 24);
    }
    float s_e   = (nt == 2) ? -2.f : -1.f;
    float swl_s = s_e * mx * (LOG2E / (127.f * 127.f));
    float m_a   = (nt == 2) ?  2.f :  1.f;
    float b_a   = (nt == 2) ? -1.f :  0.f;

    // ---- stage embedding half of x: xls[b][0:128] = bf16(word_emb[sid[b]])
    {
        int b  = tid >> 3;          // 0..63
        int c8 = tid & 7;           // 16 floats per thread
        int sid = sentences[t * 64 + b];
        const float4* ep = reinterpret_cast<const float4*>(
            word_emb + (size_t)sid * EMB + c8 * 16);
        float4 e0 = ep[0], e1 = ep[1], e2 = ep[2], e3 = ep[3];
        short8 v0, v1;
        v0[0] = (short)f2bfu(e0.x); v0[1] = (short)f2bfu(e0.y);
        v0[2] = (short)f2bfu(e0.z); v0[3] = (short)f2bfu(e0.w);
        v0[4] = (short)f2bfu(e1.x); v0[5] = (short)f2bfu(e1.y);
        v0[6] = (short)f2bfu(e1.z); v0[7] = (short)f2bfu(e1.w);
        v1[0] = (short)f2bfu(e2.x); v1[1] = (short)f2bfu(e2.y);
        v1[2] = (short)f2bfu(e2.z); v1[3] = (short)f2bfu(e2.w);
        v1[4] = (short)f2bfu(e3.x); v1[5] = (short)f2bfu(e3.y);
        v1[6] = (short)f2bfu(e3.z); v1[7] = (short)f2bfu(e3.w);
        *reinterpret_cast<short8*>(&xls[b][c8 * 16])     = v0;
        *reinterpret_cast<short8*>(&xls[b][c8 * 16 + 8]) = v1;
    }

    if (tid < 64) { reinterpret_cast<int*>(hv)[tid] = 0; }

    float cst = 0.f;
    int cid0 = words[t];
    int cid1 = words[SENT_LEN + t];
    float pl0 = pre8[(size_t)cid0 * 512 + tid];   // this lane's gate pre-input (folded)
    float pl1 = pre8[(size_t)cid1 * 512 + tid];
    int ci2 = words[2 * SENT_LEN + t];
    int ci3 = words[3 * SENT_LEN + t];
    __syncthreads();

    for (int u = 0; u < 512; u++) {          // steps 2u (A), 2u+1 (B)
        float pf0 = pre8[(size_t)ci2 * 512 + tid];
        float pf1 = pre8[(size_t)ci3 * 512 + tid];
        ci2 = words[(((u << 1) + 4) & 1023) * SENT_LEN + t];
        ci3 = words[(((u << 1) + 5) & 1023) * SENT_LEN + t];

        {   // step A: read hv[0] -> write hv[1]
            const i32x4* hp = reinterpret_cast<const i32x4*>(hv[0]);
            int a0 = 0, a1 = 0, a2 = 0, a3 = 0;
#pragma unroll
            for (int q = 0; q < 8; q++) {
                i32x4 hq = hp[q];
                a0 = __builtin_amdgcn_sdot4(hq.x, wqr[q * 4 + 0], a0, false);
                a1 = __builtin_amdgcn_sdot4(hq.y, wqr[q * 4 + 1], a1, false);
                a2 = __builtin_amdgcn_sdot4(hq.z, wqr[q * 4 + 2], a2, false);
                a3 = __builtin_amdgcn_sdot4(hq.w, wqr[q * 4 + 3], a3, false);
            }
            int s = (a0 + a1) + (a2 + a3);
            float e  = __builtin_amdgcn_exp2f(fmaf((float)s, swl_s, pl0));
            float av = m_a * rcpf(1.f + e) + b_a;     // own gate's nonlinearity
            float qi = qbcast<0>(av);                 // sig(i)
            float qf = qbcast<1>(av);                 // sig(f)
            float qg = qbcast<2>(av);                 // tanh(g)
            float qo = qbcast<3>(av);                 // sig(o)
            float c  = fmaf(qf, cst, qi * qg);
            cst = c;
            float tc = 2.f * rcpf(1.f + __builtin_amdgcn_exp2f(N2LOG2E * c)) - 1.f;
            float h  = qo * tc;
            if (nt == 0)
                hv[1][j] = (signed char)__float2int_rn(h * 127.f);
            block_sync_lds();
        }
        {   // step B: read hv[1] -> write hv[0]
            const i32x4* hp = reinterpret_cast<const i32x4*>(hv[1]);
            int a0 = 0, a1 = 0, a2 = 0, a3 = 0;
#pragma unroll
            for (int q = 0; q < 8; q++) {
                i32x4 hq = hp[q];
                a0 = __builtin_amdgcn_sdot4(hq.x, wqr[q * 4 + 0], a0, false);
                a1 = __builtin_amdgcn_sdot4(hq.y, wqr[q * 4 + 1], a1, false);
                a2 = __builtin_amdgcn_sdot4(hq.z, wqr[q * 4 + 2], a2, false);
                a3 = __builtin_amdgcn_sdot4(hq.w, wqr[q * 4 + 3], a3, false);
            }
            int s = (a0 + a1) + (a2 + a3);
            float e  = __builtin_amdgcn_exp2f(fmaf((float)s, swl_s, pl1));
            float av = m_a * rcpf(1.f + e) + b_a;
            float qi = qbcast<0>(av);
            float qf = qbcast<1>(av);
            float qg = qbcast<2>(av);
            float qo = qbcast<3>(av);
            float c  = fmaf(qf, cst, qi * qg);
            cst = c;
            float tc = 2.f * rcpf(1.f + __builtin_amdgcn_exp2f(N2LOG2E * c)) - 1.f;
            float h  = qo * tc;
            if (nt == 0) {
                hv[0][j] = (signed char)__float2int_rn(h * 127.f);
                if ((u & 7) == 7)
                    xls[u >> 3][128 + j] = f2bfu(h);   // x row's char half (bf16)
            }
            block_sync_lds();
        }
        pl0 = pf0; pl1 = pf1;
    }

    // ---- fused XW GEMM epilogue (64 rows x 1024 gates, K=256).
    // Wave w: m-tile mt = w&3, j-tiles jt = (w>>2), +2, ... (8 of 16).
    // A frags from xls (reused across j-tiles); B frags COALESCED from wihbF:
    // frag base ((jt*4+n2)*8+kt)*64, + lane -> contiguous 1KB per instruction.
    {
        int l15 = lane & 15, lq = lane >> 4;
        int mt  = w & 3;
        short8 af[8];
#pragma unroll
        for (int kt = 0; kt < 8; kt++)
            af[kt] = *reinterpret_cast<const short8*>(&xls[mt * 16 + l15][kt * 32 + lq * 8]);
        const short8* bF = reinterpret_cast<const short8*>(wihb);
#pragma unroll 1
        for (int jt = (w >> 2); jt < 16; jt += 2) {
            int j0 = jt * 16;
            const short8* bJ = bF + (size_t)jt * 4 * 8 * 64 + lane;
            f32x4 acc[4] = {{0.f,0.f,0.f,0.f},{0.f,0.f,0.f,0.f},
                            {0.f,0.f,0.f,0.f},{0.f,0.f,0.f,0.f}};
#pragma unroll
            for (int kt = 0; kt < 8; kt++) {
#pragma unroll
                for (int n2 = 0; n2 < 4; n2++) {
                    short8 bf = bJ[(n2 * 8 + kt) * 64];
                    acc[n2] = __builtin_amdgcn_mfma_f32_16x16x32_bf16(
                        af[kt], bf, acc[n2], 0, 0, 0);
                }
            }
            float bb[4];
#pragma unroll
            for (int n2 = 0; n2 < 4; n2++)
                bb[n2] = bih_w[n2 * 256 + j0 + l15] + bhh_w[n2 * 256 + j0 + l15];
#pragma unroll
            for (int r = 0; r < 4; r++) {
                int br = mt * 16 + lq * 4 + r;       // chain index within this t
                uint2 o;
                o.x = (unsigned)f2bfu((acc[0][r] + bb[0]) * LOG2E)
                    | ((unsigned)f2bfu((acc[1][r] + bb[1]) * LOG2E) << 16);
                o.y = (unsigned)f2bfu((acc[2][r] + bb[2]) * LOG2E)
                    | ((unsigned)f2bfu((acc[3][r] + bb[3]) * LOG2E) << 16);
                xw8[((size_t)br * SENT_LEN + t) * 256 + j0 + l15] = o;
            }
        }
    }
}

// ---------------- K4: word LSTM. 64 blocks x 1 chain, 1024 threads (16 waves).
// K=64 native i8 MFMA: 16 instr/wave/step — the proven issue-rate optimum (R10).
__global__ __launch_bounds__(1024, 1) void word_lstm(
        const uint2* __restrict__ xw8, const signed char* __restrict__ wq,
        const float* __restrict__ sw, float* __restrict__ h_out) {
    int b    = blockIdx.x;               // chain 0..63
    int tid  = threadIdx.x;
    int lane = tid & 63, w = tid >> 6;   // 16 waves
    int l15  = lane & 15, lq = lane >> 4;
    int j    = w * 16 + l15;

    __shared__ __align__(16) signed char hv[2][256];   // h as i8, dbuf, 512 B

    lng2 bfr[4][4];
    float swl[4];
#pragma unroll
    for (int nt = 0; nt < 4; nt++) {
        int g = nt * 256 + j;
        swl[nt] = sw[g] * (LOG2E / 127.f);
#pragma unroll
        for (int kt = 0; kt < 4; kt++)
            bfr[nt][kt] = reinterpret_cast<const lng2*>(wq + (size_t)g * HID + kt * 64 + lq * 16)[0];
    }
    if (tid < 128) { reinterpret_cast<int*>(hv)[tid] = 0; }

    const uint2* xwb = xw8 + (size_t)b * SENT_LEN * 256;   // this block's stream
    float cst = 0.f;
    uint2 xq0 = xwb[0 * 256 + j];
    uint2 xq1 = xwb[1 * 256 + j];
    uint2 xq2 = xwb[2 * 256 + j];
    uint2 xq3 = xwb[3 * 256 + j];
    __syncthreads();

    for (int u = 0; u < 128; u++) {          // steps 2u (A), 2u+1 (B)
        uint2 xn0 = xwb[((((u << 1) + 4) & 255)) * 256 + j];
        uint2 xn1 = xwb[((((u << 1) + 5) & 255)) * 256 + j];

        {   // step A: read hv[0] -> write hv[1]
            const lng2* hp = reinterpret_cast<const lng2*>(hv[0]);
            i32x4 acc[4] = {};
#pragma unroll
            for (int kt = 0; kt < 4; kt++) {
                lng2 a = hp[kt * 4 + lq];
#pragma unroll
                for (int nt = 0; nt < 4; nt++)
                    acc[nt] = mfma_i8_k64(a, bfr[nt][kt], acc[nt]);
            }
            float gi = (float)acc[0][0] * swl[0] + bf_lo(xq0.x);
            float gf = (float)acc[1][0] * swl[1] + bf_hi(xq0.x);
            float gg = (float)acc[2][0] * swl[2] + bf_lo(xq0.y);
            float go = (float)acc[3][0] * swl[3] + bf_hi(xq0.y);
            float h = lstm_act(gi, gf, gg, go, cst);
            if (lq == 0) {
                h_out[((size_t)(u << 1) * SENT_BATCH + b) * HID + j] = h;
                hv[1][j] = (signed char)__float2int_rn(h * 127.f);
            }
            block_sync_lds();
        }
        {   // step B: read hv[1] -> write hv[0]
            const lng2* hp = reinterpret_cast<const lng2*>(hv[1]);
            i32x4 acc[4] = {};
#pragma unroll
            for (int kt = 0; kt < 4; kt++) {
                lng2 a = hp[kt * 4 + lq];
#pragma unroll
                for (int nt = 0; nt < 4; nt++)
                    acc[nt] = mfma_i8_k64(a, bfr[nt][kt], acc[nt]);
            }
            float gi = (float)acc[0][0] * swl[0] + bf_lo(xq1.x);
            float gf = (float)acc[1][0] * swl[1] + bf_hi(xq1.x);
            float gg = (float)acc[2][0] * swl[2] + bf_lo(xq1.y);
            float go = (float)acc[3][0] * swl[3] + bf_hi(xq1.y);
            float h = lstm_act(gi, gf, gg, go, cst);
            if (lq == 0) {
                h_out[((size_t)((u << 1) + 1) * SENT_BATCH + b) * HID + j] = h;
                hv[0][j] = (signed char)__float2int_rn(h * 127.f);
            }
            block_sync_lds();
        }
        xq0 = xq2; xq1 = xq3; xq2 = xn0; xq3 = xn1;
    }
}

// ---------------- K5: tag projection + log_softmax. 8 rows/block (W_tag staging amortized).
__global__ __launch_bounds__(256) void tag_logsoftmax(
        const float* __restrict__ h_out, const float* __restrict__ W_tag,
        const float* __restrict__ b_tag, float* __restrict__ out) {
    __shared__ float wt_s[TAGS * 257];      // 51.4 KB
    __shared__ float hr_s[8 * HID];         // 8 KB
    int tid = threadIdx.x;
    int row0 = blockIdx.x * 8;
#pragma unroll 2
    for (int i = 0; i < TAGS; i++) wt_s[i * 257 + tid] = W_tag[i * HID + tid];
#pragma unroll
    for (int w = 0; w < 8; w++) hr_s[w * HID + tid] = h_out[(size_t)(row0 + w) * HID + tid];
    __syncthreads();

    int w4 = tid >> 6, l = tid & 63;
#pragma unroll
    for (int rep = 0; rep < 2; rep++) {
        int w = rep * 4 + w4;
        float acc = 0.f;
        if (l < TAGS) {
            acc = b_tag[l];
            const float* hr = hr_s + w * HID;
            const float* wr = wt_s + l * 257;
#pragma unroll 4
            for (int k = 0; k < HID; k++) acc += hr[k] * wr[k];
        }
        float m = (l < TAGS) ? acc : -1e30f;
#pragma unroll
        for (int off = 32; off; off >>= 1) m = fmaxf(m, __shfl_xor(m, off, 64));
        float e = (l < TAGS) ? __builtin_amdgcn_exp2f((acc - m) * LOG2E) : 0.f;
        float ssum = e;
#pragma unroll
        for (int off = 32; off; off >>= 1) ssum += __shfl_xor(ssum, off, 64);
        float lse = m + __logf(ssum);
        if (l < TAGS) out[(size_t)(row0 + w) * TAGS + l] = acc - lse;
    }
}

extern "C" void kernel_launch(void* const* d_in, const int* in_sizes, int n_in,
                              void* d_out, int out_size, void* d_ws, size_t ws_size,
                              hipStream_t stream) {
    (void)in_sizes; (void)n_in; (void)out_size; (void)ws_size;
    const int*   sentences = (const int*)d_in[0];
    const int*   words     = (const int*)d_in[1];
    const float* word_emb  = (const float*)d_in[4];
    const float* char_emb  = (const float*)d_in[5];
    const float* Wih_c     = (const float*)d_in[6];
    const float* Whh_c     = (const float*)d_in[7];
    const float* bih_c     = (const float*)d_in[8];
    const float* bhh_c     = (const float*)d_in[9];
    const float* Wih_w     = (const float*)d_in[10];
    const float* Whh_w     = (const float*)d_in[11];
    const float* bih_w     = (const float*)d_in[12];
    const float* bhh_w     = (const float*)d_in[13];
    const float* W_tag     = (const float*)d_in[14];
    const float* b_tag     = (const float*)d_in[15];
    float* out = (float*)d_out;

    char* ws = (char*)d_ws;
    size_t off = 0;
    float* pre8 = (float*)(ws + off);                 off += 128 * 512 * sizeof(float);      // 256 KB
    signed char* wq = (signed char*)(ws + off);       off += 1024 * 256;                     // 256 KB
    float* sw = (float*)(ws + off);                   off += 1024 * sizeof(float);           // 4 KB
    unsigned short* wihb = (unsigned short*)(ws + off); off += (size_t)1024 * K_IN * 2;      // 512 KB (fragment order)
    off = (off + 255) & ~(size_t)255;
    uint2* xw8 = (uint2*)(ws + off);                  off += (size_t)SENT_LEN * SENT_BATCH * 256 * sizeof(uint2);  // 33.5 MB
    float* h_out = (float*)(ws + off);                off += (size_t)SENT_LEN * SENT_BATCH * HID * sizeof(float);  // 16.8 MB

    hipLaunchKernelGGL(prep_char, dim3(128), dim3(512), 0, stream,
                       Wih_c, char_emb, bih_c, bhh_c, pre8);
    hipLaunchKernelGGL(prep_wq, dim3(1024), dim3(64), 0, stream, Whh_w, Wih_w, wq, sw, wihb);
    hipLaunchKernelGGL(char_lstm, dim3(256), dim3(512), 0, stream,
                       words, Whh_c, pre8, sentences, word_emb, wihb, bih_w, bhh_w, xw8);
    hipLaunchKernelGGL(word_lstm, dim3(SENT_BATCH), dim3(1024), 0, stream,
                       xw8, wq, sw, h_out);
    hipLaunchKernelGGL(tag_logsoftmax, dim3((SENT_LEN * SENT_BATCH) / 8), dim3(256), 0, stream,
                       h_out, W_tag, b_tag, out);
}